// Round 1
// baseline (51.221 us; speedup 1.0000x reference)
//
#include <hip/hip_runtime.h>

// DropBlock: out[b,c,h,w] = x[b,c,h,w] * mask[c,h,w]
// mask = 1 - maxpool7x7_SAME(border_zeroed(noise < gamma))
// Binary-mask trick: each 64-wide row is one u64; dilation = shifts+ORs.

constexpr int C = 256;
constexpr int B = 32;
constexpr int BATCH_PER_BLOCK = 4;

__global__ __launch_bounds__(256)
void dropblock_kernel(const float* __restrict__ x,
                      const float* __restrict__ noise,
                      float* __restrict__ out) {
    const int c = blockIdx.x;       // channel 0..255
    const int slice = blockIdx.y;   // batch slice 0..7

    __shared__ unsigned long long rowS[64];  // row-dilated center bits
    __shared__ unsigned long long dil[64];   // fully dilated bits (1 = drop)

    const int tid = threadIdx.x;
    const int lane = tid & 63;
    const int wv = tid >> 6;        // wave id 0..3

    // gamma in double, matching float64 numpy reference comparison
    const double gamma = (1.0 - 0.9) / (7.0 * 7.0) * (64.0 * 64.0) / (58.0 * 58.0);

    // ---- Phase 1: centers + row dilation (each wave does 16 rows) ----
    const float* nc = noise + (size_t)c * 4096;
    for (int h = wv; h < 64; h += 4) {
        float v = nc[h * 64 + lane];
        bool center = ((double)v < gamma) && (h >= 3) && (h <= 60)
                                          && (lane >= 3) && (lane <= 60);
        unsigned long long bits = __ballot(center);
        // log smear to +-3: t covers +-1, then t shifted +-2 covers +-3
        unsigned long long t = bits | (bits << 1) | (bits >> 1);
        unsigned long long s = t | (t << 2) | (t >> 2);
        if (lane == 0) rowS[h] = s;
    }
    __syncthreads();

    // ---- Phase 2: column dilation (threads 0..63, one row each) ----
    if (tid < 64) {
        int lo = tid - 3; if (lo < 0) lo = 0;
        int hi = tid + 3; if (hi > 63) hi = 63;
        unsigned long long d = 0;
        for (int hh = lo; hh <= hi; ++hh) d |= rowS[hh];
        dil[tid] = d;
    }
    __syncthreads();

    // ---- Phase 3: apply mask to 4 batch images, float4 vectorized ----
    const int b0 = slice * BATCH_PER_BLOCK;
    #pragma unroll
    for (int bb = 0; bb < BATCH_PER_BLOCK; ++bb) {
        const size_t img = (size_t)(b0 + bb) * C + c;   // image index
        const float4* xi = (const float4*)x + img * 1024;
        float4* oi = (float4*)out + img * 1024;
        #pragma unroll
        for (int k = 0; k < 4; ++k) {
            const int i = tid + k * 256;          // float4 index 0..1023
            float4 v = xi[i];
            const int h = i >> 4;                 // 16 float4 per row
            const int w0 = (i & 15) << 2;
            const unsigned long long bits = dil[h];
            v.x = ((bits >> (w0 + 0)) & 1ull) ? 0.0f : v.x;
            v.y = ((bits >> (w0 + 1)) & 1ull) ? 0.0f : v.y;
            v.z = ((bits >> (w0 + 2)) & 1ull) ? 0.0f : v.z;
            v.w = ((bits >> (w0 + 3)) & 1ull) ? 0.0f : v.w;
            oi[i] = v;
        }
    }
}

extern "C" void kernel_launch(void* const* d_in, const int* in_sizes, int n_in,
                              void* d_out, int out_size, void* d_ws, size_t ws_size,
                              hipStream_t stream) {
    const float* x = (const float*)d_in[0];
    const float* noise = (const float*)d_in[1];
    float* out = (float*)d_out;

    dim3 grid(C, B / BATCH_PER_BLOCK);   // 256 x 8
    dropblock_kernel<<<grid, 256, 0, stream>>>(x, noise, out);
}